// Round 7
// baseline (237.017 us; speedup 1.0000x reference)
//
#include <hip/hip_runtime.h>

typedef unsigned short u16;
typedef unsigned int   u32;
typedef short s16x8 __attribute__((ext_vector_type(8)));   // 8 x bf16 (4 VGPRs)
typedef float f32x4 __attribute__((ext_vector_type(4)));
typedef _Float16 f16x4 __attribute__((ext_vector_type(4))); // 4 x f16 (2 VGPRs)

// ---- workspace layout (bytes); total footprint 34,340,864 (proven safe) ----
#define WS_STATSV 0          // 8192 * float2
#define WS_STATSC 65536      // 8192 * float2
#define WS_WT_VQK 131072     // [512][256] bf16
#define WS_WT_CQK 393216     // [512][64]
#define WS_WT_VV  458752     // [256][256]
#define WS_WT_CV  589824     // [256][64]
#define WS_WT_OV  622592     // [256][256]
#define WS_WT_OC  753664     // [64][256]
#define WS_Q      786432     // [16][2048][128] bf16  (qv|qc per head; Q pre-scaled by log2e/8)
#define WS_K      9175040    // [16][2048][128] bf16
#define WS_VT     17563648   // [16][128][2048] f16  (V transposed per bh; d: vv 0..63, vc 64..127)
#define WS_OV     25952256   // [8192][256] bf16
#define WS_OC     30146560   // [8192][256] bf16  (ends 34,340,864)

__device__ __forceinline__ float bf2f(u16 h){
  union { u32 u; float f; } x; x.u = ((u32)h) << 16; return x.f;
}
__device__ __forceinline__ u16 f2bf(float f){
  union { float f; u32 u; } x; x.f = f;
  u32 u = x.u; u += 0x7fffu + ((u >> 16) & 1u);
  return (u16)(u >> 16);
}
__device__ __forceinline__ u16 f2h(float f){
  union { _Float16 h; u16 u; } x; x.h = (_Float16)f; return x.u;
}
__device__ __forceinline__ f32x4 mfma16(s16x8 a, s16x8 b, f32x4 c){
  return __builtin_amdgcn_mfma_f32_16x16x32_bf16(a, b, c, 0, 0, 0);
}
__device__ __forceinline__ f32x4 mfma16h(f16x4 a, f16x4 b, f32x4 c){
  return __builtin_amdgcn_mfma_f32_16x16x16f16(a, b, c, 0, 0, 0);
}

// ---------------- fused: LN row stats (bids 0..4095) + weight transpose (4096..4255) ----------------
__global__ __launch_bounds__(256) void k_prep(const float* V, const float* C,
    const float* Wvqk, const float* Wcqk, const float* Wvv, const float* Wcv,
    const float* Wov, const float* Woc, char* ws){
  int bid = blockIdx.x;
  if (bid < 4096){
    int wid = threadIdx.x >> 6, lane = threadIdx.x & 63;
    float2* sV = (float2*)(ws + WS_STATSV);
    float2* sC = (float2*)(ws + WS_STATSC);
    float s = 0.f, s2 = 0.f; int row; float2* dst; float invn;
    if (bid < 2048){
      row = bid*4 + wid;
      const float4* p = (const float4*)(V + row*256);
      float4 v = p[lane];
      s = v.x+v.y+v.z+v.w; s2 = v.x*v.x+v.y*v.y+v.z*v.z+v.w*v.w;
      dst = sV; invn = 1.0f/256.0f;
    } else {
      row = (bid-2048)*4 + wid;
      float x = C[row*64 + lane];
      s = x; s2 = x*x;
      dst = sC; invn = 1.0f/64.0f;
    }
    for (int d=1; d<64; d<<=1){ s += __shfl_xor(s,d); s2 += __shfl_xor(s2,d); }
    if (lane == 0){
      float m = s*invn; float var = s2*invn - m*m; if (var < 0.f) var = 0.f;
      float rstd = rsqrtf(var + 1e-5f);
      float2 o; o.x = rstd; o.y = -m*rstd;
      dst[row] = o;
    }
  } else {
    int tb = bid - 4096;
    const float* src; u16* dst; int K, N, rel;
    if      (tb <  64){ src=Wvqk; dst=(u16*)(ws+WS_WT_VQK); K=256; N=512; rel=tb;     }
    else if (tb <  80){ src=Wcqk; dst=(u16*)(ws+WS_WT_CQK); K=64;  N=512; rel=tb-64;  }
    else if (tb < 112){ src=Wvv;  dst=(u16*)(ws+WS_WT_VV);  K=256; N=256; rel=tb-80;  }
    else if (tb < 120){ src=Wcv;  dst=(u16*)(ws+WS_WT_CV);  K=64;  N=256; rel=tb-112; }
    else if (tb < 152){ src=Wov;  dst=(u16*)(ws+WS_WT_OV);  K=256; N=256; rel=tb-120; }
    else              { src=Woc;  dst=(u16*)(ws+WS_WT_OC);  K=256; N=64;  rel=tb-152; }
    int e = rel*2048 + threadIdx.x*8;
    int k = e / N, n0 = e % N;
    float4 t0 = *(const float4*)(src + e);
    float4 t1 = *(const float4*)(src + e + 4);
    dst[(n0+0)*K + k] = f2bf(t0.x);
    dst[(n0+1)*K + k] = f2bf(t0.y);
    dst[(n0+2)*K + k] = f2bf(t0.z);
    dst[(n0+3)*K + k] = f2bf(t0.w);
    dst[(n0+4)*K + k] = f2bf(t1.x);
    dst[(n0+5)*K + k] = f2bf(t1.y);
    dst[(n0+6)*K + k] = f2bf(t1.z);
    dst[(n0+7)*K + k] = f2bf(t1.w);
  }
}

__device__ __forceinline__ s16x8 ln_frag(const float* A, const float* g, const float* bb,
                                         int base, int k0, float2 stt){
  float4 x0 = *(const float4*)(A + base + k0);
  float4 x1 = *(const float4*)(A + base + k0 + 4);
  float4 g0 = *(const float4*)(g + k0);
  float4 g1 = *(const float4*)(g + k0 + 4);
  float4 b0 = *(const float4*)(bb + k0);
  float4 b1 = *(const float4*)(bb + k0 + 4);
  s16x8 af;
  af[0] = (short)f2bf(fmaf(fmaf(x0.x, stt.x, stt.y), g0.x, b0.x));
  af[1] = (short)f2bf(fmaf(fmaf(x0.y, stt.x, stt.y), g0.y, b0.y));
  af[2] = (short)f2bf(fmaf(fmaf(x0.z, stt.x, stt.y), g0.z, b0.z));
  af[3] = (short)f2bf(fmaf(fmaf(x0.w, stt.x, stt.y), g0.w, b0.w));
  af[4] = (short)f2bf(fmaf(fmaf(x1.x, stt.x, stt.y), g1.x, b1.x));
  af[5] = (short)f2bf(fmaf(fmaf(x1.y, stt.x, stt.y), g1.y, b1.y));
  af[6] = (short)f2bf(fmaf(fmaf(x1.z, stt.x, stt.y), g1.z, b1.z));
  af[7] = (short)f2bf(fmaf(fmaf(x1.w, stt.x, stt.y), g1.w, b1.w));
  return af;
}

// ---------------- fused projections: bids [0,512) qk-GEMM (RMS epilogue), [512,768) v-GEMM ----------------
__global__ __launch_bounds__(256) void k_proj(const float* V, const float* C,
    const float* vg, const float* vb, const float* cgam, const float* cbet,
    const float* bvqk, const float* bcqk, const float* rmsv, const float* rmsc,
    const float* bvv, const float* bcv, char* ws){
  __shared__ float ssl[2][32];
  int bid = blockIdx.x;
  int tid = threadIdx.x, lane = tid & 63, w = tid >> 6;
  int c = lane & 15, q = lane >> 4;

  if (bid < 512){
    bool csd = bid >= 256;
    int rb = (bid & 255) * 32;
    const float* A   = csd ? C : V;
    int K            = csd ? 64 : 256;
    const float2* st = (const float2*)(ws + (csd ? WS_STATSC : WS_STATSV));
    const float* g   = csd ? cgam : vg;
    const float* bb  = csd ? cbet : vb;
    const u16* Wt    = (const u16*)(ws + (csd ? WS_WT_CQK : WS_WT_VQK));
    const float* bias= csd ? bcqk : bvqk;
    const float* rms = csd ? rmsc : rmsv;
    int dOff         = csd ? 64 : 0;

    int s = w & 1, cgp = w >> 1;
    int r0 = rb + s*16;
    int row = r0 + c;
    float2 stt = st[row];
    int j0 = cgp * 256;

    f32x4 acc[16];
    #pragma unroll
    for (int f=0; f<16; f++){ f32x4 z = {0.f,0.f,0.f,0.f}; acc[f] = z; }

    int nkc = K >> 5;
    for (int kc=0; kc<nkc; kc++){
      int k0 = kc*32 + q*8;
      s16x8 af = ln_frag(A, g, bb, row*K, k0, stt);
      #pragma unroll
      for (int f=0; f<16; f++){
        s16x8 bfr = *(const s16x8*)(Wt + (j0 + f*16 + c)*K + k0);
        acc[f] = mfma16(af, bfr, acc[f]);
      }
    }

    float ss[4] = {0.f,0.f,0.f,0.f};
    float rsv[16];
    #pragma unroll
    for (int f=0; f<16; f++){
      int j = j0 + f*16 + c;
      float bsv = bias[j]; rsv[f] = rms[j];
      #pragma unroll
      for (int i=0;i<4;i++){ acc[f][i] += bsv; ss[i] += acc[f][i]*acc[f][i]; }
    }
    #pragma unroll
    for (int d=1; d<16; d<<=1){
      #pragma unroll
      for (int i=0;i<4;i++) ss[i] += __shfl_xor(ss[i], d);
    }
    if (c == 0){
      #pragma unroll
      for (int i=0;i<4;i++) ssl[cgp][s*16 + q*4 + i] = ss[i];
    }
    __syncthreads();
    float rmsr[4];
    #pragma unroll
    for (int i=0;i<4;i++){
      int rl = s*16 + q*4 + i;
      float tot = ssl[0][rl] + ssl[1][rl];
      rmsr[i] = rsqrtf(tot * (1.0f/512.0f) + 1e-6f);
    }
    u16* dstb = (u16*)(ws + (cgp==0 ? WS_Q : WS_K));
    // fold 1/sqrt(64) AND log2(e) into Q so attention uses exp2 with no extra mult
    float qs = (cgp==0) ? 0.125f*1.44269504f : 1.0f;
    #pragma unroll
    for (int f=0; f<16; f++){
      int j = f*16 + c;
      int head = j >> 6, dd = (j & 63) + dOff;
      #pragma unroll
      for (int i=0;i<4;i++){
        int r = r0 + q*4 + i;
        int b_ = r >> 11, n = r & 2047;
        dstb[((b_*4 + head)*2048 + n)*128 + dd] = f2bf(acc[f][i]*rmsr[i]*rsv[f]*qs);
      }
    }
  } else {
    int vb2 = bid - 512;
    bool csd = vb2 >= 128;
    int rb = (vb2 & 127) * 64;
    const float* A   = csd ? C : V;
    int K            = csd ? 64 : 256;
    const float2* st = (const float2*)(ws + (csd ? WS_STATSC : WS_STATSV));
    const float* g   = csd ? cgam : vg;
    const float* bb  = csd ? cbet : vb;
    const u16* Wt    = (const u16*)(ws + (csd ? WS_WT_CV : WS_WT_VV));
    const float* bias= csd ? bcv : bvv;
    int dOff         = csd ? 64 : 0;

    int r0 = rb + w*16, row = r0 + c;
    float2 stt = st[row];

    f32x4 acc[16];
    #pragma unroll
    for (int f=0; f<16; f++){ f32x4 z = {0.f,0.f,0.f,0.f}; acc[f] = z; }

    int nkc = K >> 5;
    for (int kc=0; kc<nkc; kc++){
      int k0 = kc*32 + q*8;
      s16x8 af = ln_frag(A, g, bb, row*K, k0, stt);
      #pragma unroll
      for (int f=0; f<16; f++){
        s16x8 bfr = *(const s16x8*)(Wt + (f*16 + c)*K + k0);
        acc[f] = mfma16(af, bfr, acc[f]);
      }
    }
    u16* vt = (u16*)(ws + WS_VT);   // f16 payload now
    int r = r0 + q*4;
    int b_ = r >> 11, n = r & 2047;
    #pragma unroll
    for (int f=0; f<16; f++){
      int j = f*16 + c;
      float bv_ = bias[j];
      int head = j >> 6, dd = (j & 63) + dOff;
      ushort4 pk;
      pk.x = f2h(acc[f][0] + bv_); pk.y = f2h(acc[f][1] + bv_);
      pk.z = f2h(acc[f][2] + bv_); pk.w = f2h(acc[f][3] + bv_);
      *(ushort4*)(vt + ((b_*4 + head)*128 + dd)*2048 + n) = pk;
    }
  }
}

// ---------------- flash attention v6: 32 Q-rows/wave x 16 KV-cols/wave (KV-split),
// QK 16x16x32 bf16, PV 16x16x16 f16. 2 waves/block, grid 1024 -> 2048 waves, 4 blk/CU.
// No-max softmax (scores bounded), dbuf K/V register-staged prefetch, 1 barrier/iter.
__global__ __launch_bounds__(128, 2) void k_attn(char* ws){
  const u16* Qw = (const u16*)(ws + WS_Q);
  const u16* Kw = (const u16*)(ws + WS_K);
  const u16* Vt = (const u16*)(ws + WS_VT);   // f16
  u16* Ov = (u16*)(ws + WS_OV);
  u16* Oc = (u16*)(ws + WS_OC);

  __shared__ u16 Ks[2][4096];     // 16 KB: 2 bufs x (32 rows x 16 chunks x 8), xor-swizzled
  __shared__ u16 VsF[2][4608];    // 18 KB: 2 bufs x 128 d-rows x stride 36 (32 cols + pad), f16
  __shared__ u16 Psf[2][640];     // per-wave P: 32 rows x stride 20 (16 cols + pad), f16

  int bh = blockIdx.x & 15, qb = blockIdx.x >> 4;   // qb 0..63, 32 rows each
  int tid = threadIdx.x, lane = tid & 63, w = tid >> 6;   // w = nhalf (KV col half)
  int c = lane & 15, q = lane >> 4;
  int qr0 = qb*32;

  // Q fragments direct from global (read-once): rows qr0 + s2*16 + c
  s16x8 qf[2][4];
  #pragma unroll
  for (int s2=0;s2<2;s2++)
    #pragma unroll
    for (int kc=0;kc<4;kc++)
      qf[s2][kc] = *(const s16x8*)(Qw + (bh*2048 + qr0 + s2*16 + c)*128 + kc*32 + q*8);

  // staging maps (128 threads stage full 32x128 K tile + 128x32 V tile)
  const u16* ksrc[4]; const u16* vsrc[4]; int vdst[4];
  #pragma unroll
  for (int i=0;i<4;i++){
    int s = i*128 + tid;
    { int r = s >> 4, j = (s & 15) ^ (r & 15);        // K: 32 rows x 16 chunks, xor swizzle
      ksrc[i] = Kw + (bh*2048 + r)*128 + j*8; }
    { int r = s >> 2, j = s & 3;                      // V: 128 d-rows x 4 chunks (8 cols)
      vsrc[i] = Vt + (size_t)(bh*128 + r)*2048 + j*8;
      vdst[i] = r*36 + j*8; }
  }

  f32x4 o[2][8];
  float lsum[2][4];
  #pragma unroll
  for (int s2=0;s2<2;s2++){
    #pragma unroll
    for (int f8=0;f8<8;f8++){ f32x4 z = {0.f,0.f,0.f,0.f}; o[s2][f8] = z; }
    #pragma unroll
    for (int i=0;i<4;i++) lsum[s2][i] = 0.f;
  }

  // prologue: tile 0 -> regs -> buf 0
  uint4 kr[4], vr[4];
  #pragma unroll
  for (int i=0;i<4;i++){ kr[i] = *(const uint4*)(ksrc[i]); vr[i] = *(const uint4*)(vsrc[i]); }
  #pragma unroll
  for (int i=0;i<4;i++){
    *(uint4*)&Ks[0][(i*128 + tid)*8] = kr[i];
    *(uint4*)&VsF[0][vdst[i]] = vr[i];
  }

  for (int t=0; t<64; t++){
    int bi = t & 1;
    __syncthreads();                 // buf bi staged & visible
    if (t < 63){                     // prefetch next tile into registers
      int tn = t + 1;
      #pragma unroll
      for (int i=0;i<4;i++){
        kr[i] = *(const uint4*)(ksrc[i] + tn*4096);  // K tile stride: 32 rows * 128
        vr[i] = *(const uint4*)(vsrc[i] + tn*32);    // V tile stride: 32 cols
      }
    }
    // K fragments for this wave's 16 cols: rows w*16+c, chunks kc*4+q (xor ^row-c)
    s16x8 kf[4];
    #pragma unroll
    for (int kc=0;kc<4;kc++)
      kf[kc] = *(const s16x8*)(&Ks[bi][((w*16+c)*16 + (((kc*4+q) ^ c) & 15))*8]);

    // QK^T: 2 row-slabs x 16 cols
    f32x4 sfr[2];
    #pragma unroll
    for (int s2=0;s2<2;s2++){ f32x4 z = {0.f,0.f,0.f,0.f}; sfr[s2] = z; }
    #pragma unroll
    for (int s2=0;s2<2;s2++)
      #pragma unroll
      for (int kc=0;kc<4;kc++)
        sfr[s2] = mfma16(qf[s2][kc], kf[kc], sfr[s2]);

    // p = exp2(s) -> f16 into per-wave P (rows = Q rows, cols = 16 KV cols)
    #pragma unroll
    for (int s2=0;s2<2;s2++){
      #pragma unroll
      for (int i=0;i<4;i++){
        float p = exp2f(sfr[s2][i]);
        lsum[s2][i] += p;
        Psf[w][(s2*16 + q*4 + i)*20 + c] = f2h(p);
      }
    }
    // V fragments (f16, b64): B[k=col][n=d]: Vs[d = f8*16+c][col = w*16 + q*4 + j]
    // PV: A-frag from Psf: P[m=c][k=q*4+j]
    #pragma unroll
    for (int s2=0;s2<2;s2++){
      f16x4 pf = *(const f16x4*)(&Psf[w][(s2*16 + c)*20 + q*4]);
      #pragma unroll
      for (int f8=0;f8<8;f8++){
        f16x4 vf = *(const f16x4*)(&VsF[bi][(f8*16 + c)*36 + w*16 + q*4]);
        o[s2][f8] = mfma16h(pf, vf, o[s2][f8]);
      }
    }
    if (t < 63){                     // stage prefetched tile into other buffer
      #pragma unroll
      for (int i=0;i<4;i++){
        *(uint4*)&Ks[bi^1][(i*128 + tid)*8] = kr[i];
        *(uint4*)&VsF[bi^1][vdst[i]] = vr[i];
      }
    }
  }

  // reduce lsum over this wave's 16 cols
  #pragma unroll
  for (int s2=0;s2<2;s2++)
    #pragma unroll
    for (int d=1; d<16; d<<=1)
      #pragma unroll
      for (int i=0;i<4;i++) lsum[s2][i] += __shfl_xor(lsum[s2][i], d);

  // combine the two KV-halves: wave 1 -> LDS, wave 0 adds, normalizes, stores
  __syncthreads();                      // done with Ks/Vs tile data
  float* OX = (float*)&Ks[0][0];        // 16 KB exchange buffer (overlay)
  float* LX = (float*)&Psf[0][0];       // 32-float lsum exchange (overlay)
  if (w == 1){
    #pragma unroll
    for (int s2=0;s2<2;s2++)
      #pragma unroll
      for (int f8=0;f8<8;f8++)
        *(f32x4*)(OX + ((s2*8 + f8)*64 + lane)*4) = o[s2][f8];
    if (c == 0)
      #pragma unroll
      for (int s2=0;s2<2;s2++)
        #pragma unroll
        for (int i=0;i<4;i++)
          LX[s2*16 + q*4 + i] = lsum[s2][i];
  }
  __syncthreads();
  if (w == 0){
    int b_ = bh >> 2, h = bh & 3;
    #pragma unroll
    for (int s2=0;s2<2;s2++){
      float inv[4];
      #pragma unroll
      for (int i=0;i<4;i++)
        inv[i] = 1.0f / (lsum[s2][i] + LX[s2*16 + q*4 + i]);
      #pragma unroll
      for (int f8=0;f8<8;f8++){
        f32x4 oo = o[s2][f8];
        f32x4 ox = *(const f32x4*)(OX + ((s2*8 + f8)*64 + lane)*4);
        int col = f8*16 + c;
        u16* dst = (col < 64) ? Ov : Oc;
        int dd = col & 63;
        #pragma unroll
        for (int i=0;i<4;i++){
          int n = qr0 + s2*16 + q*4 + i;
          dst[(b_*2048 + n)*256 + h*64 + dd] = f2bf((oo[i] + ox[i]) * inv[i]);
        }
      }
    }
  }
}

// ---------------- fused output projections: bids [0,256) N=256, [256,384) N=64 ----------------
__global__ __launch_bounds__(256) void k_out(const u16* Av, const u16* Wtv, const float* bv,
                                             const u16* Ac, const u16* Wtc, const float* bc,
                                             float* out){
  int bid = blockIdx.x;
  int tid = threadIdx.x, lane = tid & 63, w = tid >> 6;
  int c = lane & 15, q = lane >> 4;
  if (bid < 256){
    int rb = bid * 32;
    int s = w & 1, cgp = w >> 1;
    int r0 = rb + s*16, row = r0 + c;
    f32x4 acc[8];
    #pragma unroll
    for (int f=0; f<8; f++){ f32x4 z = {0.f,0.f,0.f,0.f}; acc[f] = z; }
    for (int kc=0; kc<8; kc++){
      int k0 = kc*32 + q*8;
      s16x8 af = *(const s16x8*)(Av + row*256 + k0);
      #pragma unroll
      for (int f=0; f<8; f++){
        s16x8 bfr = *(const s16x8*)(Wtv + (cgp*128 + f*16 + c)*256 + k0);
        acc[f] = mfma16(af, bfr, acc[f]);
      }
    }
    #pragma unroll
    for (int f=0; f<8; f++){
      int j = cgp*128 + f*16 + c;
      float bb = bv[j];
      #pragma unroll
      for (int i=0;i<4;i++)
        out[(r0 + q*4 + i)*256 + j] = acc[f][i] + bb;
    }
  } else {
    int rb = (bid - 256) * 64;
    int r0 = rb + w*16, row = r0 + c;
    f32x4 acc[4];
    #pragma unroll
    for (int f=0; f<4; f++){ f32x4 z = {0.f,0.f,0.f,0.f}; acc[f] = z; }
    for (int kc=0; kc<8; kc++){
      int k0 = kc*32 + q*8;
      s16x8 af = *(const s16x8*)(Ac + row*256 + k0);
      #pragma unroll
      for (int f=0; f<4; f++){
        s16x8 bfr = *(const s16x8*)(Wtc + (f*16 + c)*256 + k0);
        acc[f] = mfma16(af, bfr, acc[f]);
      }
    }
    float* oc = out + 2097152;
    #pragma unroll
    for (int f=0; f<4; f++){
      int j = f*16 + c;
      float bb = bc[j];
      #pragma unroll
      for (int i=0;i<4;i++)
        oc[(r0 + q*4 + i)*64 + j] = acc[f][i] + bb;
    }
  }
}

extern "C" void kernel_launch(void* const* d_in, const int* in_sizes, int n_in,
                              void* d_out, int out_size, void* d_ws, size_t ws_size,
                              hipStream_t stream){
  (void)in_sizes; (void)n_in; (void)out_size; (void)ws_size;
  const float* V    = (const float*)d_in[0];
  const float* C    = (const float*)d_in[1];
  const float* vng  = (const float*)d_in[2];
  const float* vnb  = (const float*)d_in[3];
  const float* cng  = (const float*)d_in[4];
  const float* cnb  = (const float*)d_in[5];
  const float* Wvqk = (const float*)d_in[6];
  const float* bvqk = (const float*)d_in[7];
  const float* rmsv = (const float*)d_in[8];
  const float* Wcqk = (const float*)d_in[9];
  const float* bcqk = (const float*)d_in[10];
  const float* rmsc = (const float*)d_in[11];
  const float* Wvv  = (const float*)d_in[12];
  const float* bvv  = (const float*)d_in[13];
  const float* Wcv  = (const float*)d_in[14];
  const float* bcv  = (const float*)d_in[15];
  const float* Wov  = (const float*)d_in[16];
  const float* bov  = (const float*)d_in[17];
  const float* Woc  = (const float*)d_in[18];
  const float* boc  = (const float*)d_in[19];
  char* ws = (char*)d_ws;
  float* out = (float*)d_out;

  k_prep<<<4256, 256, 0, stream>>>(V, C, Wvqk, Wcqk, Wvv, Wcv, Wov, Woc, ws);
  k_proj<<<768, 256, 0, stream>>>(V, C, vng, vnb, cng, cnb,
                                  bvqk, bcqk, rmsv, rmsc, bvv, bcv, ws);
  k_attn<<<1024, 128, 0, stream>>>(ws);
  k_out<<<384, 256, 0, stream>>>((const u16*)(ws + WS_OV), (const u16*)(ws + WS_WT_OV), bov,
                                 (const u16*)(ws + WS_OC), (const u16*)(ws + WS_WT_OC), boc,
                                 out);
}

// Round 8
// 227.964 us; speedup vs baseline: 1.0397x; 1.0397x over previous
//
#include <hip/hip_runtime.h>

typedef unsigned short u16;
typedef unsigned int   u32;
typedef short s16x8 __attribute__((ext_vector_type(8)));   // 8 x bf16 (4 VGPRs)
typedef float f32x4 __attribute__((ext_vector_type(4)));

// ---- workspace layout (bytes); total footprint 34,340,864 (proven safe) ----
#define WS_STATSV 0          // 8192 * float2
#define WS_STATSC 65536      // 8192 * float2
#define WS_WT_VQK 131072     // [512][256] bf16
#define WS_WT_CQK 393216     // [512][64]
#define WS_WT_VV  458752     // [256][256]
#define WS_WT_CV  589824     // [256][64]
#define WS_WT_OV  622592     // [256][256]
#define WS_WT_OC  753664     // [64][256]
#define WS_Q      786432     // [16][2048][128] bf16  (qv|qc per head; Q pre-scaled by log2e/8)
#define WS_K      9175040    // [16][2048][128] bf16
#define WS_VT     17563648   // [16][128][2048] bf16 (V^T per bh; d: vv 0..63, vc 64..127)
#define WS_OV     25952256   // [8192][256] bf16
#define WS_OC     30146560   // [8192][256] bf16  (ends 34,340,864)

__device__ __forceinline__ float bf2f(u16 h){
  union { u32 u; float f; } x; x.u = ((u32)h) << 16; return x.f;
}
__device__ __forceinline__ u16 f2bf(float f){
  union { float f; u32 u; } x; x.f = f;
  u32 u = x.u; u += 0x7fffu + ((u >> 16) & 1u);
  return (u16)(u >> 16);
}
__device__ __forceinline__ f32x4 mfma16(s16x8 a, s16x8 b, f32x4 c){
  return __builtin_amdgcn_mfma_f32_16x16x32_bf16(a, b, c, 0, 0, 0);
}

// ---------------- fused: LN row stats (bids 0..4095) + weight transpose (4096..4255) ----------------
__global__ __launch_bounds__(256) void k_prep(const float* V, const float* C,
    const float* Wvqk, const float* Wcqk, const float* Wvv, const float* Wcv,
    const float* Wov, const float* Woc, char* ws){
  int bid = blockIdx.x;
  if (bid < 4096){
    int wid = threadIdx.x >> 6, lane = threadIdx.x & 63;
    float2* sV = (float2*)(ws + WS_STATSV);
    float2* sC = (float2*)(ws + WS_STATSC);
    float s = 0.f, s2 = 0.f; int row; float2* dst; float invn;
    if (bid < 2048){
      row = bid*4 + wid;
      const float4* p = (const float4*)(V + row*256);
      float4 v = p[lane];
      s = v.x+v.y+v.z+v.w; s2 = v.x*v.x+v.y*v.y+v.z*v.z+v.w*v.w;
      dst = sV; invn = 1.0f/256.0f;
    } else {
      row = (bid-2048)*4 + wid;
      float x = C[row*64 + lane];
      s = x; s2 = x*x;
      dst = sC; invn = 1.0f/64.0f;
    }
    for (int d=1; d<64; d<<=1){ s += __shfl_xor(s,d); s2 += __shfl_xor(s2,d); }
    if (lane == 0){
      float m = s*invn; float var = s2*invn - m*m; if (var < 0.f) var = 0.f;
      float rstd = rsqrtf(var + 1e-5f);
      float2 o; o.x = rstd; o.y = -m*rstd;
      dst[row] = o;
    }
  } else {
    int tb = bid - 4096;
    const float* src; u16* dst; int K, N, rel;
    if      (tb <  64){ src=Wvqk; dst=(u16*)(ws+WS_WT_VQK); K=256; N=512; rel=tb;     }
    else if (tb <  80){ src=Wcqk; dst=(u16*)(ws+WS_WT_CQK); K=64;  N=512; rel=tb-64;  }
    else if (tb < 112){ src=Wvv;  dst=(u16*)(ws+WS_WT_VV);  K=256; N=256; rel=tb-80;  }
    else if (tb < 120){ src=Wcv;  dst=(u16*)(ws+WS_WT_CV);  K=64;  N=256; rel=tb-112; }
    else if (tb < 152){ src=Wov;  dst=(u16*)(ws+WS_WT_OV);  K=256; N=256; rel=tb-120; }
    else              { src=Woc;  dst=(u16*)(ws+WS_WT_OC);  K=256; N=64;  rel=tb-152; }
    int e = rel*2048 + threadIdx.x*8;
    int k = e / N, n0 = e % N;
    float4 t0 = *(const float4*)(src + e);
    float4 t1 = *(const float4*)(src + e + 4);
    dst[(n0+0)*K + k] = f2bf(t0.x);
    dst[(n0+1)*K + k] = f2bf(t0.y);
    dst[(n0+2)*K + k] = f2bf(t0.z);
    dst[(n0+3)*K + k] = f2bf(t0.w);
    dst[(n0+4)*K + k] = f2bf(t1.x);
    dst[(n0+5)*K + k] = f2bf(t1.y);
    dst[(n0+6)*K + k] = f2bf(t1.z);
    dst[(n0+7)*K + k] = f2bf(t1.w);
  }
}

__device__ __forceinline__ s16x8 ln_frag(const float* A, const float* g, const float* bb,
                                         int base, int k0, float2 stt){
  float4 x0 = *(const float4*)(A + base + k0);
  float4 x1 = *(const float4*)(A + base + k0 + 4);
  float4 g0 = *(const float4*)(g + k0);
  float4 g1 = *(const float4*)(g + k0 + 4);
  float4 b0 = *(const float4*)(bb + k0);
  float4 b1 = *(const float4*)(bb + k0 + 4);
  s16x8 af;
  af[0] = (short)f2bf(fmaf(fmaf(x0.x, stt.x, stt.y), g0.x, b0.x));
  af[1] = (short)f2bf(fmaf(fmaf(x0.y, stt.x, stt.y), g0.y, b0.y));
  af[2] = (short)f2bf(fmaf(fmaf(x0.z, stt.x, stt.y), g0.z, b0.z));
  af[3] = (short)f2bf(fmaf(fmaf(x0.w, stt.x, stt.y), g0.w, b0.w));
  af[4] = (short)f2bf(fmaf(fmaf(x1.x, stt.x, stt.y), g1.x, b1.x));
  af[5] = (short)f2bf(fmaf(fmaf(x1.y, stt.x, stt.y), g1.y, b1.y));
  af[6] = (short)f2bf(fmaf(fmaf(x1.z, stt.x, stt.y), g1.z, b1.z));
  af[7] = (short)f2bf(fmaf(fmaf(x1.w, stt.x, stt.y), g1.w, b1.w));
  return af;
}

// ---------------- fused projections v2 (more waves):
// bids [0,512) V-qk 16-row, [512,1024) C-qk 16-row, [1024,1280) V-v 32-row, [1280,1536) C-v 32-row
__global__ __launch_bounds__(256) void k_proj(const float* V, const float* C,
    const float* vg, const float* vb, const float* cgam, const float* cbet,
    const float* bvqk, const float* bcqk, const float* rmsv, const float* rmsc,
    const float* bvv, const float* bcv, char* ws){
  __shared__ float ssl[4][16];
  int bid = blockIdx.x;
  int tid = threadIdx.x, lane = tid & 63, w = tid >> 6;
  int c = lane & 15, q = lane >> 4;

  if (bid < 1024){
    bool csd = bid >= 512;
    int rb = (bid & 511) * 16;
    const float* A   = csd ? C : V;
    int K            = csd ? 64 : 256;
    const float2* st = (const float2*)(ws + (csd ? WS_STATSC : WS_STATSV));
    const float* g   = csd ? cgam : vg;
    const float* bb  = csd ? cbet : vb;
    const u16* Wt    = (const u16*)(ws + (csd ? WS_WT_CQK : WS_WT_VQK));
    const float* bias= csd ? bcqk : bvqk;
    const float* rms = csd ? rmsc : rmsv;
    int dOff         = csd ? 64 : 0;

    int row = rb + c;
    float2 stt = st[row];
    int j0 = w * 128;                 // wave = 128-col group of the 512

    f32x4 acc[8];
    #pragma unroll
    for (int f=0; f<8; f++){ f32x4 z = {0.f,0.f,0.f,0.f}; acc[f] = z; }

    int nkc = K >> 5;
    for (int kc=0; kc<nkc; kc++){
      int k0 = kc*32 + q*8;
      s16x8 af = ln_frag(A, g, bb, row*K, k0, stt);
      #pragma unroll
      for (int f=0; f<8; f++){
        s16x8 bfr = *(const s16x8*)(Wt + (j0 + f*16 + c)*K + k0);
        acc[f] = mfma16(af, bfr, acc[f]);
      }
    }

    float ss[4] = {0.f,0.f,0.f,0.f};
    float rsv[8];
    #pragma unroll
    for (int f=0; f<8; f++){
      int j = j0 + f*16 + c;
      float bsv = bias[j]; rsv[f] = rms[j];
      #pragma unroll
      for (int i=0;i<4;i++){ acc[f][i] += bsv; ss[i] += acc[f][i]*acc[f][i]; }
    }
    #pragma unroll
    for (int d=1; d<16; d<<=1){
      #pragma unroll
      for (int i=0;i<4;i++) ss[i] += __shfl_xor(ss[i], d);
    }
    if (c == 0){
      #pragma unroll
      for (int i=0;i<4;i++) ssl[w][q*4 + i] = ss[i];
    }
    __syncthreads();
    float rmsr[4];
    #pragma unroll
    for (int i=0;i<4;i++){
      int rl = q*4 + i;
      float tot = ssl[0][rl] + ssl[1][rl] + ssl[2][rl] + ssl[3][rl];
      rmsr[i] = rsqrtf(tot * (1.0f/512.0f) + 1e-6f);
    }
    u16* dstb = (u16*)(ws + (w < 2 ? WS_Q : WS_K));
    // fold 1/sqrt(64) AND log2(e) into Q so attention uses exp2 with no extra mult
    float qs = (w < 2) ? 0.125f*1.44269504f : 1.0f;
    #pragma unroll
    for (int f=0; f<8; f++){
      int jj = (j0 + f*16 + c) & 255;      // col within Q or K half
      int head = jj >> 6, dd = (jj & 63) + dOff;
      #pragma unroll
      for (int i=0;i<4;i++){
        int r = rb + q*4 + i;
        int b_ = r >> 11, n = r & 2047;
        dstb[((b_*4 + head)*2048 + n)*128 + dd] = f2bf(acc[f][i]*rmsr[i]*rsv[f]*qs);
      }
    }
  } else {
    int vb2 = bid - 1024;
    bool csd = vb2 >= 256;
    int rb = (vb2 & 255) * 32;
    const float* A   = csd ? C : V;
    int K            = csd ? 64 : 256;
    const float2* st = (const float2*)(ws + (csd ? WS_STATSC : WS_STATSV));
    const float* g   = csd ? cgam : vg;
    const float* bb  = csd ? cbet : vb;
    const u16* Wt    = (const u16*)(ws + (csd ? WS_WT_CV : WS_WT_VV));
    const float* bias= csd ? bcv : bvv;
    int dOff         = csd ? 64 : 0;

    int s = w & 1, cgp = w >> 1;       // 2 slabs x 2 colgroups(128)
    int r0 = rb + s*16, row = r0 + c;
    float2 stt = st[row];
    int j0 = cgp * 128;

    f32x4 acc[8];
    #pragma unroll
    for (int f=0; f<8; f++){ f32x4 z = {0.f,0.f,0.f,0.f}; acc[f] = z; }

    int nkc = K >> 5;
    for (int kc=0; kc<nkc; kc++){
      int k0 = kc*32 + q*8;
      s16x8 af = ln_frag(A, g, bb, row*K, k0, stt);
      #pragma unroll
      for (int f=0; f<8; f++){
        s16x8 bfr = *(const s16x8*)(Wt + (j0 + f*16 + c)*K + k0);
        acc[f] = mfma16(af, bfr, acc[f]);
      }
    }
    u16* vt = (u16*)(ws + WS_VT);
    int r = r0 + q*4;
    int b_ = r >> 11, n = r & 2047;
    #pragma unroll
    for (int f=0; f<8; f++){
      int j = j0 + f*16 + c;
      float bv_ = bias[j];
      int head = j >> 6, dd = (j & 63) + dOff;
      ushort4 pk;
      pk.x = f2bf(acc[f][0] + bv_); pk.y = f2bf(acc[f][1] + bv_);
      pk.z = f2bf(acc[f][2] + bv_); pk.w = f2bf(acc[f][3] + bv_);
      *(ushort4*)(vt + ((b_*4 + head)*128 + dd)*2048 + n) = pk;
    }
  }
}

// ---------------- flash attention (R6 version, proven 73.3 us): 16 Q-rows/wave, 4 waves/block,
// grid 512 -> 2048 waves (2/SIMD), no-max softmax, dbuf register-staged prefetch, XOR swizzle.
__global__ __launch_bounds__(256) void k_attn(char* ws){
  const u16* Qw = (const u16*)(ws + WS_Q);
  const u16* Kw = (const u16*)(ws + WS_K);
  const u16* Vt = (const u16*)(ws + WS_VT);
  u16* Ov = (u16*)(ws + WS_OV);
  u16* Oc = (u16*)(ws + WS_OC);
  __shared__ u16 Ks[2][4096];   // 2 bufs x 512 chunks x 8 (32 rows x 128 d)
  __shared__ u16 Vs[2][4096];   // 2 bufs x 512 chunks (128 d x 32 n)
  __shared__ u16 Ps[4][640];    // per-wave 16 x 40 (stride-40: ~2-way banks)

  int bh = blockIdx.x & 15, qb = blockIdx.x >> 4;
  int tid = threadIdx.x, lane = tid & 63, w = tid >> 6;
  int c = lane & 15, q = lane >> 4;
  int qr0 = qb*64 + w*16;

  // Q fragments direct from global (read-once); A-layout rows qr0+c
  s16x8 qf[4];
  #pragma unroll
  for (int kc=0;kc<4;kc++)
    qf[kc] = *(const s16x8*)(Qw + (bh*2048 + qr0 + c)*128 + kc*32 + q*8);

  // per-thread staging map: chunk s = i*256 + tid; XOR swizzle (r,j)
  const u16* ksrc[2]; const u16* vsrc[2];
  #pragma unroll
  for (int i=0;i<2;i++){
    int s = i*256 + tid;
    { int r = s >> 4, j = (s & 15) ^ (r & 15);        // K: 32 rows x 16 chunks
      ksrc[i] = Kw + (bh*2048 + r)*128 + j*8; }
    { int r = s >> 2, j = (s & 3) ^ ((r >> 1) & 3);   // V: 128 rows x 4 chunks
      vsrc[i] = Vt + (bh*128 + r)*2048 + j*8; }
  }

  f32x4 o[8];
  float lsum[4] = {0.f,0.f,0.f,0.f};
  #pragma unroll
  for (int f8=0;f8<8;f8++){ f32x4 z = {0.f,0.f,0.f,0.f}; o[f8] = z; }

  // prologue: tile 0 -> regs -> buf 0
  uint4 kr[2], vr[2];
  #pragma unroll
  for (int i=0;i<2;i++){ kr[i] = *(const uint4*)(ksrc[i]); vr[i] = *(const uint4*)(vsrc[i]); }
  #pragma unroll
  for (int i=0;i<2;i++){
    *(uint4*)&Ks[0][(i*256 + tid)*8] = kr[i];
    *(uint4*)&Vs[0][(i*256 + tid)*8] = vr[i];
  }

  for (int t=0; t<64; t++){
    int bi = t & 1;
    __syncthreads();                 // buf bi staged & visible to all waves
    if (t < 63){                     // prefetch next tile into registers
      int tn = t + 1;
      #pragma unroll
      for (int i=0;i<2;i++){
        kr[i] = *(const uint4*)(ksrc[i] + tn*4096);  // K tile stride: 32 rows * 128
        vr[i] = *(const uint4*)(vsrc[i] + tn*32);    // V tile stride: 32 cols
      }
    }
    // K fragments: row f*16+c, chunk kc*4+q, swizzle ^c
    s16x8 kf[2][4];
    #pragma unroll
    for (int f=0;f<2;f++)
      #pragma unroll
      for (int kc=0;kc<4;kc++)
        kf[f][kc] = *(const s16x8*)(&Ks[bi][((f*16+c)*16 + (((kc*4+q) ^ c) & 15))*8]);
    // V fragments: row f8*16+c, chunk q, swizzle ^((c>>1)&3)
    s16x8 vf[8];
    #pragma unroll
    for (int f8=0;f8<8;f8++)
      vf[f8] = *(const s16x8*)(&Vs[bi][((f8*16+c)*4 + ((q ^ ((c>>1)&3)) & 3))*8]);

    // QK^T (Q pre-scaled by log2e/8)
    f32x4 sfr[2];
    #pragma unroll
    for (int f=0;f<2;f++){ f32x4 z = {0.f,0.f,0.f,0.f}; sfr[f] = z; }
    #pragma unroll
    for (int f=0;f<2;f++)
      #pragma unroll
      for (int kc=0;kc<4;kc++)
        sfr[f] = mfma16(qf[kc], kf[f][kc], sfr[f]);

    // p = exp2(s); no max subtraction (scores bounded; scale folded into Q)
    #pragma unroll
    for (int f=0;f<2;f++){
      #pragma unroll
      for (int i=0;i<4;i++){
        float p = exp2f(sfr[f][i]);
        lsum[i] += p;
        Ps[w][(q*4 + i)*40 + f*16 + c] = f2bf(p);
      }
    }
    // per-wave LDS round-trip: C-layout -> A-layout (no barrier needed)
    s16x8 pf = *(const s16x8*)(&Ps[w][c*40 + q*8]);
    #pragma unroll
    for (int f8=0;f8<8;f8++)
      o[f8] = mfma16(pf, vf[f8], o[f8]);

    if (t < 63){                     // stage prefetched tile into the other buffer
      #pragma unroll
      for (int i=0;i<2;i++){
        *(uint4*)&Ks[bi^1][(i*256 + tid)*8] = kr[i];
        *(uint4*)&Vs[bi^1][(i*256 + tid)*8] = vr[i];
      }
    }
  }

  #pragma unroll
  for (int d=1; d<16; d<<=1)
    #pragma unroll
    for (int i=0;i<4;i++) lsum[i] += __shfl_xor(lsum[i], d);
  float inv[4];
  #pragma unroll
  for (int i=0;i<4;i++) inv[i] = 1.0f/lsum[i];

  int b_ = bh >> 2, h = bh & 3;
  #pragma unroll
  for (int f8=0;f8<8;f8++){
    int col = f8*16 + c;
    u16* dst = (col < 64) ? Ov : Oc;
    int dd = col & 63;
    #pragma unroll
    for (int i=0;i<4;i++){
      int n = qr0 + q*4 + i;
      dst[(b_*2048 + n)*256 + h*64 + dd] = f2bf(o[f8][i]*inv[i]);
    }
  }
}

// ---------------- fused output projections v2 (more waves):
// bids [0,512) N=256 16-row blocks (4 waves x 64-col groups); [512,640) N=64 64-row blocks.
__global__ __launch_bounds__(256) void k_out(const u16* Av, const u16* Wtv, const float* bv,
                                             const u16* Ac, const u16* Wtc, const float* bc,
                                             float* out){
  int bid = blockIdx.x;
  int tid = threadIdx.x, lane = tid & 63, w = tid >> 6;
  int c = lane & 15, q = lane >> 4;
  if (bid < 512){
    int rb = bid * 16;
    int row = rb + c;
    int j0 = w * 64;
    f32x4 acc[4];
    #pragma unroll
    for (int f=0; f<4; f++){ f32x4 z = {0.f,0.f,0.f,0.f}; acc[f] = z; }
    for (int kc=0; kc<8; kc++){
      int k0 = kc*32 + q*8;
      s16x8 af = *(const s16x8*)(Av + row*256 + k0);
      #pragma unroll
      for (int f=0; f<4; f++){
        s16x8 bfr = *(const s16x8*)(Wtv + (j0 + f*16 + c)*256 + k0);
        acc[f] = mfma16(af, bfr, acc[f]);
      }
    }
    #pragma unroll
    for (int f=0; f<4; f++){
      int j = j0 + f*16 + c;
      float bb = bv[j];
      #pragma unroll
      for (int i=0;i<4;i++)
        out[(rb + q*4 + i)*256 + j] = acc[f][i] + bb;
    }
  } else {
    int rb = (bid - 512) * 64;
    int r0 = rb + w*16, row = r0 + c;
    f32x4 acc[4];
    #pragma unroll
    for (int f=0; f<4; f++){ f32x4 z = {0.f,0.f,0.f,0.f}; acc[f] = z; }
    for (int kc=0; kc<8; kc++){
      int k0 = kc*32 + q*8;
      s16x8 af = *(const s16x8*)(Ac + row*256 + k0);
      #pragma unroll
      for (int f=0; f<4; f++){
        s16x8 bfr = *(const s16x8*)(Wtc + (f*16 + c)*256 + k0);
        acc[f] = mfma16(af, bfr, acc[f]);
      }
    }
    float* oc = out + 2097152;
    #pragma unroll
    for (int f=0; f<4; f++){
      int j = f*16 + c;
      float bb = bc[j];
      #pragma unroll
      for (int i=0;i<4;i++)
        oc[(r0 + q*4 + i)*64 + j] = acc[f][i] + bb;
    }
  }
}

extern "C" void kernel_launch(void* const* d_in, const int* in_sizes, int n_in,
                              void* d_out, int out_size, void* d_ws, size_t ws_size,
                              hipStream_t stream){
  (void)in_sizes; (void)n_in; (void)out_size; (void)ws_size;
  const float* V    = (const float*)d_in[0];
  const float* C    = (const float*)d_in[1];
  const float* vng  = (const float*)d_in[2];
  const float* vnb  = (const float*)d_in[3];
  const float* cng  = (const float*)d_in[4];
  const float* cnb  = (const float*)d_in[5];
  const float* Wvqk = (const float*)d_in[6];
  const float* bvqk = (const float*)d_in[7];
  const float* rmsv = (const float*)d_in[8];
  const float* Wcqk = (const float*)d_in[9];
  const float* bcqk = (const float*)d_in[10];
  const float* rmsc = (const float*)d_in[11];
  const float* Wvv  = (const float*)d_in[12];
  const float* bvv  = (const float*)d_in[13];
  const float* Wcv  = (const float*)d_in[14];
  const float* bcv  = (const float*)d_in[15];
  const float* Wov  = (const float*)d_in[16];
  const float* bov  = (const float*)d_in[17];
  const float* Woc  = (const float*)d_in[18];
  const float* boc  = (const float*)d_in[19];
  char* ws = (char*)d_ws;
  float* out = (float*)d_out;

  k_prep<<<4256, 256, 0, stream>>>(V, C, Wvqk, Wcqk, Wvv, Wcv, Wov, Woc, ws);
  k_proj<<<1536, 256, 0, stream>>>(V, C, vng, vnb, cng, cnb,
                                   bvqk, bcqk, rmsv, rmsc, bvv, bcv, ws);
  k_attn<<<512, 256, 0, stream>>>(ws);
  k_out<<<640, 256, 0, stream>>>((const u16*)(ws + WS_OV), (const u16*)(ws + WS_WT_OV), bov,
                                 (const u16*)(ws + WS_OC), (const u16*)(ws + WS_WT_OC), boc,
                                 out);
}